// Round 12
// baseline (363.960 us; speedup 1.0000x reference)
//
#include <hip/hip_runtime.h>

#define NEGV -10000000000.0f

typedef _Float16 half8 __attribute__((ext_vector_type(8)));
typedef float f32x4 __attribute__((ext_vector_type(4)));

__device__ __forceinline__ void gld16(const void* g, void* l) {
  __builtin_amdgcn_global_load_lds((const __attribute__((address_space(1))) void*)g,
                                   (__attribute__((address_space(3))) void*)l,
                                   16, 0, 0);
}

__device__ __forceinline__ float fast_tanh(float x) {
  const float e = __expf(2.0f * x);
  return 1.0f - 2.0f * __builtin_amdgcn_rcpf(e + 1.0f);
}

// ---------------------------------------------------------------------------
// PREP (one launch): blocks [0,128) hproj | [128,1152) wconv | rest encconv.
// ---------------------------------------------------------------------------
__global__ __launch_bounds__(256) void prep_kernel(
    const float* __restrict__ enc, _Float16* __restrict__ enc16,
    const float* __restrict__ We, _Float16* __restrict__ W16T,
    const float* __restrict__ hidden, const float* __restrict__ W_h,
    const float* __restrict__ b_h, const float* __restrict__ b_e,
    float* __restrict__ hpb) {
  __shared__ float tile[32][33];
  const int bid = blockIdx.x;
  const int tid = threadIdx.x;

  if (bid < 128) {
    // ---- hproj ----
    const int b = bid >> 2;
    const int h = ((bid & 3) << 8) | tid;
    const float* hb = hidden + b * 1024;
    float a0 = 0.f, a1 = 0.f, a2 = 0.f, a3 = 0.f;
    #pragma unroll 4
    for (int k = 0; k < 1024; k += 4) {
      a0 = fmaf(hb[k + 0], W_h[(size_t)(k + 0) * 1024 + h], a0);
      a1 = fmaf(hb[k + 1], W_h[(size_t)(k + 1) * 1024 + h], a1);
      a2 = fmaf(hb[k + 2], W_h[(size_t)(k + 2) * 1024 + h], a2);
      a3 = fmaf(hb[k + 3], W_h[(size_t)(k + 3) * 1024 + h], a3);
    }
    hpb[b * 1024 + h] = b_h[h] + b_e[h] + ((a0 + a1) + (a2 + a3));
  } else if (bid < 128 + 1024) {
    // ---- wconv: W16T[n][k] = (fp16) W_e[k][n] ----
    const int tb = bid - 128;
    const int n0 = (tb & 31) << 5, k0 = (tb >> 5) << 5;
    const int tx = tid & 31, ty = tid >> 5;  // 32 x 8
    #pragma unroll
    for (int i = 0; i < 4; ++i) {
      const int r = ty + (i << 3);
      tile[r][tx] = We[(size_t)(k0 + r) * 1024 + n0 + tx];
    }
    __syncthreads();
    #pragma unroll
    for (int i = 0; i < 4; ++i) {
      const int r = ty + (i << 3);
      W16T[(size_t)(n0 + r) * 1024 + k0 + tx] = (_Float16)tile[tx][r];
    }
  } else {
    // ---- encconv: fp32 -> fp16 ----
    const size_t base = ((size_t)(bid - 1152) * 256 + tid) * 8;
    const float4 x = *(const float4*)(enc + base);
    const float4 y = *(const float4*)(enc + base + 4);
    half8 h;
    h[0] = (_Float16)x.x; h[1] = (_Float16)x.y; h[2] = (_Float16)x.z; h[3] = (_Float16)x.w;
    h[4] = (_Float16)y.x; h[5] = (_Float16)y.y; h[6] = (_Float16)y.z; h[7] = (_Float16)y.w;
    *(half8*)(enc16 + base) = h;
  }
}

// ---------------------------------------------------------------------------
// FUSED GEMM, B-operand DIRECT FROM L2 (no LDS for B):
//   logits[b,s] = mask ? v . tanh(hpb[b,:] + enc[b,s,:]@W_e) : NEG
// BM=256, BN=256 (4 panels), BK=32, 512 threads, 8 waves 2Mx4N, per-wave
// 128x64 (acc[8][4]).
//  - A: gld_lds into triple-buffered 16KB tiles, stage t+2, swizzle
//    g ^= (row>>1)&3 both sides (0-conflict, R4-R6). 8 ds_read_b128/wave/tile.
//  - B: W16T is 2MB -> L2-resident per XCD. Each wave loads its 4 B-frags
//    directly global->VGPR (16 rows x 64B contiguous per load = fully
//    line-utilized), prefetched 1 tile ahead (bf_next). Removes 32KB reads +
//    16KB writes per tile from the LDS pipe -> LDS (~770cyc) < MFMA (1242).
//  - Ledger (FIFO: [sA(t+1)x2, bf(t)x4, sA(t+2)x2, bf(t+1)x4]): the MFMA
//    data-dep wait on bf(t) retires sA(t+1) (FIFO-earlier), so the tile-end
//    barrier publishes A; explicit vmcnt(6) kept as motion fence + invariant.
//    Never drains in main loop.
// ---------------------------------------------------------------------------
__global__ __launch_bounds__(512, 2) void attn_gemm8_kernel(
    const _Float16* __restrict__ enc16, const _Float16* __restrict__ W16T,
    const float* __restrict__ hpb, const float* __restrict__ v,
    const int* __restrict__ mask, float* __restrict__ logits) {
  __shared__ __align__(16) _Float16 Abuf[3][256 * 32];  // 48 KB
  __shared__ float hp_s[1024];
  __shared__ float vh_s[1024];
  __shared__ float red[1024];

  const int tid = threadIdx.x;
  const int wid = tid >> 6;
  const int lane = tid & 63;
  const int l15 = lane & 15;
  const int qq = lane >> 4;        // 16B granule within the 64B row
  const int wr = wid >> 2;         // 0..1: rows [wr*128, +128)
  const int wc = wid & 3;          // 0..3: cols [wc*64, +64) within the panel
  const int m0 = blockIdx.x << 8;  // 256 rows per block
  const int b = blockIdx.x >> 3;   // 8 blocks per batch

  for (int i = tid; i < 1024; i += 512) {
    hp_s[i] = hpb[(b << 10) + i];
    vh_s[i] = v[i];
  }

  // ---- A staging constants ----
  const int r0 = tid >> 2;                     // row for issue 0 (0..127)
  const int r1 = r0 + 128;                     // row for issue 1 (same swz bits)
  const int g0 = tid & 3;                      // 16B granule within 64B row
  const int sc = (g0 ^ ((r0 >> 1) & 3)) << 4;  // inverse-swizzled source col
  const int ldsoff0 = (wid << 10);
  const int ldsoff1 = (wid << 10) + 8192;

  const char* encb = (const char*)(enc16 + (size_t)m0 * 1024);
  const char* wb0 = (const char*)W16T;

  auto stageA = [&](int buf, int t) {
    const int colb = ((t & 31) << 6) + sc;  // BK=32 -> 64B k-tile per row
    char* base = (char*)(&Abuf[buf][0]);
    gld16(encb + (size_t)r0 * 2048 + colb, base + ldsoff0);
    gld16(encb + (size_t)r1 * 2048 + colb, base + ldsoff1);
  };

  // ---- B direct-load constants (byte offset of each frag's row+granule) ----
  int bofG[4];
  #pragma unroll
  for (int ni = 0; ni < 4; ++ni)
    bofG[ni] = (((wc << 6) + (ni << 4) + l15) << 11) + (qq << 4);

  auto loadB = [&](half8* dst, int t) {
    const char* wb = wb0 + ((size_t)(t >> 5) << 19) + ((t & 31) << 6);
    #pragma unroll
    for (int ni = 0; ni < 4; ++ni) dst[ni] = *(const half8*)(wb + bofG[ni]);
  };

  // ---- A read-side offsets (loop-invariant, swizzled) ----
  int aoff[2][4];
  #pragma unroll
  for (int mh = 0; mh < 2; ++mh)
    #pragma unroll
    for (int mi = 0; mi < 4; ++mi) {
      const int row = (wr << 7) + (mh << 6) + (mi << 4) + l15;
      aoff[mh][mi] = (row << 6) + ((qq ^ ((row >> 1) & 3)) << 4);
    }

  f32x4 acc[8][4];
  float rowsum[8][4];
  #pragma unroll
  for (int mi = 0; mi < 8; ++mi)
    #pragma unroll
    for (int j = 0; j < 4; ++j) {
      acc[mi][j] = (f32x4){0.f, 0.f, 0.f, 0.f};
      rowsum[mi][j] = 0.f;
    }

  // ---- prologue: stage A tiles 0,1; load bf(0); full drain once ----
  half8 bf[4], bfn[4];
  stageA(0, 0);
  stageA(1, 1);
  loadB(bf, 0);
  __syncthreads();

  int bi = 0;
  #pragma unroll 1
  for (int t = 0; t < 128; ++t) {
    const int bi2 = (bi >= 1) ? bi - 1 : bi + 2;  // (bi+2)%3
    const char* A = (const char*)(&Abuf[bi][0]);
    half8 a0[4], a1[4];

    // ---- issue all 8 A ds_reads (compiler places counted lgkm waits) ----
    #pragma unroll
    for (int mi = 0; mi < 4; ++mi) a0[mi] = *(const half8*)(A + aoff[0][mi]);
    #pragma unroll
    for (int mi = 0; mi < 4; ++mi) a1[mi] = *(const half8*)(A + aoff[1][mi]);

    // ---- stage A(t+2) to LDS; prefetch B(t+1) to regs ----
    if (t < 126) stageA(bi2, t + 2);
    if (t < 127) loadB(bfn, t + 1);

    // ---- MFMA clusters; A-reads + bf(t) dep-waits drain underneath ----
    __builtin_amdgcn_s_setprio(1);
    #pragma unroll
    for (int mi = 0; mi < 4; ++mi)
      #pragma unroll
      for (int ni = 0; ni < 4; ++ni)
        acc[mi][ni] = __builtin_amdgcn_mfma_f32_16x16x32_f16(a0[mi], bf[ni], acc[mi][ni], 0, 0, 0);
    #pragma unroll
    for (int mi = 0; mi < 4; ++mi)
      #pragma unroll
      for (int ni = 0; ni < 4; ++ni)
        acc[4 + mi][ni] = __builtin_amdgcn_mfma_f32_16x16x32_f16(a1[mi], bf[ni], acc[4 + mi][ni], 0, 0, 0);
    __builtin_amdgcn_s_setprio(0);

    // ---- rotate B prefetch ----
    if (t < 127) {
      #pragma unroll
      for (int ni = 0; ni < 4; ++ni) bf[ni] = bfn[ni];
    }

    // ---- single tile-end sync: counted vmcnt (motion fence) + barrier ----
    if (t < 126) asm volatile("s_waitcnt vmcnt(6)" ::: "memory");
    else         asm volatile("s_waitcnt vmcnt(0)" ::: "memory");
    __builtin_amdgcn_s_barrier();

    // ---- per-panel epilogue: rowsum += tanh(acc + hproj) * v ----
    if ((t & 31) == 31) {
      const int nt = t >> 5;
      const int hb = (nt << 8) + (wc << 6);
      #pragma unroll
      for (int ni = 0; ni < 4; ++ni) {
        const int h = hb + (ni << 4) + l15;
        const float hv = hp_s[h];
        const float vv = vh_s[h];
        #pragma unroll
        for (int mi = 0; mi < 8; ++mi) {
          #pragma unroll
          for (int r = 0; r < 4; ++r)
            rowsum[mi][r] += fast_tanh(acc[mi][ni][r] + hv) * vv;
          acc[mi][ni] = (f32x4){0.f, 0.f, 0.f, 0.f};
        }
      }
    }
    bi = (bi >= 2) ? 0 : bi + 1;
  }

  // ---- reduce across the 16 column-lanes of each wave ----
  #pragma unroll
  for (int mi = 0; mi < 8; ++mi)
    #pragma unroll
    for (int r = 0; r < 4; ++r) {
      float s = rowsum[mi][r];
      s += __shfl_xor(s, 1);
      s += __shfl_xor(s, 2);
      s += __shfl_xor(s, 4);
      s += __shfl_xor(s, 8);
      rowsum[mi][r] = s;
    }
  __syncthreads();
  if (l15 == 0) {
    #pragma unroll
    for (int mi = 0; mi < 8; ++mi)
      #pragma unroll
      for (int r = 0; r < 4; ++r) {
        const int row = (wr << 7) + (mi << 4) + (qq << 2) + r;
        red[(row << 2) + wc] = rowsum[mi][r];
      }
  }
  __syncthreads();
  if (tid < 256) {
    const float s = red[tid << 2] + red[(tid << 2) + 1] + red[(tid << 2) + 2] + red[(tid << 2) + 3];
    const int m = m0 + tid;
    logits[m] = (mask[(b << 11) + (m & 2047)] == 0) ? NEGV : s;
  }
}

// ---------------------------------------------------------------------------
// softmax over S=2048 per batch row -> attention weights (output 1)
// ---------------------------------------------------------------------------
__global__ void softmax_kernel(const float* __restrict__ logits, float* __restrict__ wout) {
  __shared__ float red[4];
  const int b = blockIdx.x, tid = threadIdx.x;
  const int wid = tid >> 6, lane = tid & 63;
  const float* lb = logits + b * 2048;
  float x[8];
  #pragma unroll
  for (int j = 0; j < 8; ++j) x[j] = lb[tid + j * 256];
  float m = x[0];
  #pragma unroll
  for (int j = 1; j < 8; ++j) m = fmaxf(m, x[j]);
  #pragma unroll
  for (int off = 32; off > 0; off >>= 1) m = fmaxf(m, __shfl_xor(m, off));
  if (lane == 0) red[wid] = m;
  __syncthreads();
  m = fmaxf(fmaxf(red[0], red[1]), fmaxf(red[2], red[3]));
  __syncthreads();
  float e[8];
  float s = 0.f;
  #pragma unroll
  for (int j = 0; j < 8; ++j) { e[j] = expf(x[j] - m); s += e[j]; }
  #pragma unroll
  for (int off = 32; off > 0; off >>= 1) s += __shfl_xor(s, off);
  if (lane == 0) red[wid] = s;
  __syncthreads();
  s = red[0] + red[1] + red[2] + red[3];
  const float inv = 1.0f / s;
  #pragma unroll
  for (int j = 0; j < 8; ++j) wout[b * 2048 + tid + j * 256] = e[j] * inv;
}

// ---------------------------------------------------------------------------
// context from fp16 enc: ctx[b,e] = sum_s w[b,s] * enc16[b,s,e]
// ---------------------------------------------------------------------------
__global__ void context16_kernel(const _Float16* __restrict__ enc16,
                                 const float* __restrict__ wout, float* __restrict__ ctx) {
  const int b = blockIdx.x >> 4;
  const int ch = blockIdx.x & 15;
  const int tl = threadIdx.x & 127;  // e-granule: 8 cols
  const int sh = threadIdx.x >> 7;   // 0/1: s interleave
  float a[8] = {0.f, 0.f, 0.f, 0.f, 0.f, 0.f, 0.f, 0.f};
  #pragma unroll 1
  for (int i = 0; i < 64; ++i) {
    const int s = (ch << 7) + (i << 1) + sh;
    const float w = wout[(b << 11) + s];
    const half8 r = *(const half8*)(enc16 + (((size_t)(b << 11) + s) << 10) + (tl << 3));
    #pragma unroll
    for (int j = 0; j < 8; ++j) a[j] = fmaf(w, (float)r[j], a[j]);
  }
  float* c = ctx + (b << 10) + (tl << 3);
  #pragma unroll
  for (int j = 0; j < 8; ++j) atomicAdd(c + j, a[j]);
}

// ---------------------------------------------------------------------------
extern "C" void kernel_launch(void* const* d_in, const int* in_sizes, int n_in,
                              void* d_out, int out_size, void* d_ws, size_t ws_size,
                              hipStream_t stream) {
  const float* hidden = (const float*)d_in[0];
  const float* enc    = (const float*)d_in[1];
  const int*   mask   = (const int*)d_in[2];
  const float* W_h    = (const float*)d_in[3];
  const float* b_h    = (const float*)d_in[4];
  const float* W_e    = (const float*)d_in[5];
  const float* b_e    = (const float*)d_in[6];
  const float* v      = (const float*)d_in[7];

  float* ctx  = (float*)d_out;              // context: 32*1024 floats
  float* wout = (float*)d_out + 32 * 1024;  // attention weights: 32*2048 floats

  char* ws = (char*)d_ws;
  const size_t ENC16_BYTES = 134217728ULL;  // 32*2048*1024 fp16
  _Float16* enc16 = (_Float16*)ws;
  _Float16* W16T  = (_Float16*)(ws + ENC16_BYTES);
  float* hpb      = (float*)(ws + ENC16_BYTES + 2097152);
  float* logits   = (float*)(ws + ENC16_BYTES + 2097152 + 131072);

  hipMemsetAsync(ctx, 0, 32 * 1024 * sizeof(float), stream);
  hipLaunchKernelGGL(prep_kernel, dim3(1152 + 32768), dim3(256), 0, stream,
                     enc, enc16, W_e, W16T, hidden, W_h, b_h, b_e, hpb);
  hipLaunchKernelGGL(attn_gemm8_kernel, dim3(256), dim3(512), 0, stream,
                     enc16, W16T, hpb, v, mask, logits);
  hipLaunchKernelGGL(softmax_kernel, dim3(32), dim3(256), 0, stream, logits, wout);
  hipLaunchKernelGGL(context16_kernel, dim3(512), dim3(256), 0, stream, enc16, wout, ctx);
}

// Round 13
// 296.264 us; speedup vs baseline: 1.2285x; 1.2285x over previous
//
#include <hip/hip_runtime.h>

#define NEGV -10000000000.0f

typedef _Float16 half8 __attribute__((ext_vector_type(8)));
typedef float f32x4 __attribute__((ext_vector_type(4)));

__device__ __forceinline__ void gld16(const void* g, void* l) {
  __builtin_amdgcn_global_load_lds((const __attribute__((address_space(1))) void*)g,
                                   (__attribute__((address_space(3))) void*)l,
                                   16, 0, 0);
}

__device__ __forceinline__ float fast_tanh(float x) {
  const float e = __expf(2.0f * x);
  return 1.0f - 2.0f * __builtin_amdgcn_rcpf(e + 1.0f);
}

// ---------------------------------------------------------------------------
// PREP (one launch): blocks [0,128) hproj | [128,1152) wconv | rest encconv.
// ---------------------------------------------------------------------------
__global__ __launch_bounds__(256) void prep_kernel(
    const float* __restrict__ enc, _Float16* __restrict__ enc16,
    const float* __restrict__ We, _Float16* __restrict__ W16T,
    const float* __restrict__ hidden, const float* __restrict__ W_h,
    const float* __restrict__ b_h, const float* __restrict__ b_e,
    float* __restrict__ hpb) {
  __shared__ float tile[32][33];
  const int bid = blockIdx.x;
  const int tid = threadIdx.x;

  if (bid < 128) {
    // ---- hproj ----
    const int b = bid >> 2;
    const int h = ((bid & 3) << 8) | tid;
    const float* hb = hidden + b * 1024;
    float a0 = 0.f, a1 = 0.f, a2 = 0.f, a3 = 0.f;
    #pragma unroll 4
    for (int k = 0; k < 1024; k += 4) {
      a0 = fmaf(hb[k + 0], W_h[(size_t)(k + 0) * 1024 + h], a0);
      a1 = fmaf(hb[k + 1], W_h[(size_t)(k + 1) * 1024 + h], a1);
      a2 = fmaf(hb[k + 2], W_h[(size_t)(k + 2) * 1024 + h], a2);
      a3 = fmaf(hb[k + 3], W_h[(size_t)(k + 3) * 1024 + h], a3);
    }
    hpb[b * 1024 + h] = b_h[h] + b_e[h] + ((a0 + a1) + (a2 + a3));
  } else if (bid < 128 + 1024) {
    // ---- wconv: W16T[n][k] = (fp16) W_e[k][n] ----
    const int tb = bid - 128;
    const int n0 = (tb & 31) << 5, k0 = (tb >> 5) << 5;
    const int tx = tid & 31, ty = tid >> 5;  // 32 x 8
    #pragma unroll
    for (int i = 0; i < 4; ++i) {
      const int r = ty + (i << 3);
      tile[r][tx] = We[(size_t)(k0 + r) * 1024 + n0 + tx];
    }
    __syncthreads();
    #pragma unroll
    for (int i = 0; i < 4; ++i) {
      const int r = ty + (i << 3);
      W16T[(size_t)(n0 + r) * 1024 + k0 + tx] = (_Float16)tile[tx][r];
    }
  } else {
    // ---- encconv: fp32 -> fp16 ----
    const size_t base = ((size_t)(bid - 1152) * 256 + tid) * 8;
    const float4 x = *(const float4*)(enc + base);
    const float4 y = *(const float4*)(enc + base + 4);
    half8 h;
    h[0] = (_Float16)x.x; h[1] = (_Float16)x.y; h[2] = (_Float16)x.z; h[3] = (_Float16)x.w;
    h[4] = (_Float16)y.x; h[5] = (_Float16)y.y; h[6] = (_Float16)y.z; h[7] = (_Float16)y.w;
    *(half8*)(enc16 + base) = h;
  }
}

// ---------------------------------------------------------------------------
// FUSED GEMM, 2 BLOCKS/CU (occupancy fix; schedule = R9's proven single
// barrier + counted vmcnt, swizzle unchanged):
//   logits[b,s] = mask ? v . tanh(hpb[b,:] + enc[b,s,:]@W_e) : NEG
// BM=128, BN=256 (4 panels), BK=32, 256 threads = 4 waves as 1Mx4N,
// per-wave 128x64 (acc[8][4]).  LDS = 3x8K A + 3x16K B + 4K hp + 2K v(fp16)
// = 79872 B <= 80KB  ->  2 independent blocks per CU: one block's MFMA phase
// overlaps the other's LDS-read phase (per-tile barriers only sync within a
// block). R9 ran 1 block/CU and measured full LDS/MFMA serialization
// (~2900cyc/tile vs 1242 MFMA content) -- this is the m97-style inter-block
// overlap, which our 96KB+ LDS footprint had been denying.
// Staging: 6 gld_lds/thread/tile (A 2 + B 4), stage t+2; tile-end vmcnt(6)
// retires stage(t+1), stage(t+2)'s 6 stay in flight (never drains).
// Swizzle: g ^= (row>>1)&3 on stage-source AND ds_read (0-conflict, R4-R9).
// v stored fp16 in LDS (error ~3e-4 logits, << threshold) to fit 80KB.
// ---------------------------------------------------------------------------
__global__ __launch_bounds__(256, 2) void attn_gemm8_kernel(
    const _Float16* __restrict__ enc16, const _Float16* __restrict__ W16T,
    const float* __restrict__ hpb, const float* __restrict__ v,
    const int* __restrict__ mask, float* __restrict__ logits) {
  __shared__ __align__(16) _Float16 Abuf[3][128 * 32];  // 24 KB
  __shared__ __align__(16) _Float16 Bbuf[3][256 * 32];  // 48 KB
  __shared__ float hp_s[1024];                          // 4 KB
  __shared__ _Float16 vh_s[1024];                       // 2 KB

  const int tid = threadIdx.x;
  const int wid = tid >> 6;
  const int lane = tid & 63;
  const int l15 = lane & 15;
  const int qq = lane >> 4;        // 16B granule within the 64B row
  const int wc = wid;              // 0..3: cols [wc*64, +64) within the panel
  const int m0 = blockIdx.x << 7;  // 128 rows per block
  const int b = blockIdx.x >> 4;   // 16 blocks per batch

  for (int i = tid; i < 1024; i += 256) {
    hp_s[i] = hpb[(b << 10) + i];
    vh_s[i] = (_Float16)v[i];
  }

  // ---- staging constants ----
  const int rA = tid >> 2;                     // A row (0..63 / 64..127 via i)
  const int g0 = tid & 3;                      // 16B granule within 64B row
  const int ldsoff = (wid << 10);              // wave-uniform LDS dest base

  const char* encb = (const char*)(enc16 + (size_t)m0 * 1024);
  const char* wb0 = (const char*)W16T;

  // A tile: 128 rows x 32 k = 8KB = 512 granules; 2 gld16/thread
  auto stageA = [&](int buf, int t) {
    const int colb = (t & 31) << 6;
    char* base = (char*)(&Abuf[buf][0]) + ldsoff;
    #pragma unroll
    for (int i = 0; i < 2; ++i) {
      const int row = rA + (i << 6);
      const int col = colb + (((g0 ^ ((row >> 1) & 3))) << 4);
      gld16(encb + (size_t)row * 2048 + col, base + (i << 12));
    }
  };
  // B tile: 256 rows x 32 k = 16KB = 1024 granules; 4 gld16/thread
  auto stageB = [&](int buf, int t) {
    const char* wb = wb0 + ((size_t)(t >> 5) << 19);  // panel * 256*2048 B
    const int colb = (t & 31) << 6;
    char* base = (char*)(&Bbuf[buf][0]) + ldsoff;
    #pragma unroll
    for (int i = 0; i < 4; ++i) {
      const int np = rA + (i << 6);
      const int col = colb + (((g0 ^ ((np >> 1) & 3))) << 4);
      gld16(wb + (size_t)np * 2048 + col, base + (i << 12));
    }
  };

  // ---- read-side offsets (loop-invariant, swizzled) ----
  int aoff[2][4], boff[4];
  #pragma unroll
  for (int mh = 0; mh < 2; ++mh)
    #pragma unroll
    for (int mi = 0; mi < 4; ++mi) {
      const int row = (mh << 6) + (mi << 4) + l15;  // all 4 waves share A rows
      aoff[mh][mi] = (row << 6) + ((qq ^ ((row >> 1) & 3)) << 4);
    }
  #pragma unroll
  for (int ni = 0; ni < 4; ++ni) {
    const int np = (wc << 6) + (ni << 4) + l15;
    boff[ni] = (np << 6) + ((qq ^ ((np >> 1) & 3)) << 4);
  }

  f32x4 acc[8][4];
  float rowsum[8][4];
  #pragma unroll
  for (int mi = 0; mi < 8; ++mi)
    #pragma unroll
    for (int j = 0; j < 4; ++j) {
      acc[mi][j] = (f32x4){0.f, 0.f, 0.f, 0.f};
      rowsum[mi][j] = 0.f;
    }

  // ---- prologue: stage tiles 0,1; __syncthreads drains vm+lgkm fully ----
  stageA(0, 0); stageB(0, 0);
  stageA(1, 1); stageB(1, 1);
  __syncthreads();

  int bi = 0;
  #pragma unroll 1
  for (int t = 0; t < 128; ++t) {
    const int bi2 = (bi >= 1) ? bi - 1 : bi + 2;  // (bi+2)%3
    const char* A = (const char*)(&Abuf[bi][0]);
    const char* B = (const char*)(&Bbuf[bi][0]);
    half8 a0[4], a1[4], bf[4];

    // ---- issue all 12 ds_reads up front (compiler places counted waits) ----
    #pragma unroll
    for (int mi = 0; mi < 4; ++mi) a0[mi] = *(const half8*)(A + aoff[0][mi]);
    #pragma unroll
    for (int ni = 0; ni < 4; ++ni) bf[ni] = *(const half8*)(B + boff[ni]);
    #pragma unroll
    for (int mi = 0; mi < 4; ++mi) a1[mi] = *(const half8*)(A + aoff[1][mi]);

    // ---- stage tile t+2 (writes buf bi2; no overlap with reads of bi) ----
    if (t < 126) { stageA(bi2, t + 2); stageB(bi2, t + 2); }

    // ---- MFMA clusters; reads drain underneath via per-operand waits ----
    __builtin_amdgcn_s_setprio(1);
    #pragma unroll
    for (int mi = 0; mi < 4; ++mi)
      #pragma unroll
      for (int ni = 0; ni < 4; ++ni)
        acc[mi][ni] = __builtin_amdgcn_mfma_f32_16x16x32_f16(a0[mi], bf[ni], acc[mi][ni], 0, 0, 0);
    #pragma unroll
    for (int mi = 0; mi < 4; ++mi)
      #pragma unroll
      for (int ni = 0; ni < 4; ++ni)
        acc[4 + mi][ni] = __builtin_amdgcn_mfma_f32_16x16x32_f16(a1[mi], bf[ni], acc[4 + mi][ni], 0, 0, 0);
    __builtin_amdgcn_s_setprio(0);

    // ---- single tile-end sync: counted vmcnt (motion fence) + barrier ----
    if (t < 126) asm volatile("s_waitcnt vmcnt(6)" ::: "memory");
    else         asm volatile("s_waitcnt vmcnt(0)" ::: "memory");
    __builtin_amdgcn_s_barrier();

    // ---- per-panel epilogue: rowsum += tanh(acc + hproj) * v ----
    if ((t & 31) == 31) {
      const int nt = t >> 5;
      const int hb = (nt << 8) + (wc << 6);
      #pragma unroll
      for (int ni = 0; ni < 4; ++ni) {
        const int h = hb + (ni << 4) + l15;
        const float hv = hp_s[h];
        const float vv = (float)vh_s[h];
        #pragma unroll
        for (int mi = 0; mi < 8; ++mi) {
          #pragma unroll
          for (int r = 0; r < 4; ++r)
            rowsum[mi][r] += fast_tanh(acc[mi][ni][r] + hv) * vv;
          acc[mi][ni] = (f32x4){0.f, 0.f, 0.f, 0.f};
        }
      }
    }
    bi = (bi >= 2) ? 0 : bi + 1;
  }

  // ---- reduce across the 16 column-lanes of each wave ----
  #pragma unroll
  for (int mi = 0; mi < 8; ++mi)
    #pragma unroll
    for (int r = 0; r < 4; ++r) {
      float s = rowsum[mi][r];
      s += __shfl_xor(s, 1);
      s += __shfl_xor(s, 2);
      s += __shfl_xor(s, 4);
      s += __shfl_xor(s, 8);
      rowsum[mi][r] = s;
    }
  // cross-wave reduce through LDS; Abuf is dead now -- alias it
  float* red = (float*)(&Abuf[0][0]);
  __syncthreads();
  if (l15 == 0) {
    #pragma unroll
    for (int mi = 0; mi < 8; ++mi)
      #pragma unroll
      for (int r = 0; r < 4; ++r) {
        const int row = (mi << 4) + (qq << 2) + r;
        red[(row << 2) + wc] = rowsum[mi][r];
      }
  }
  __syncthreads();
  if (tid < 128) {
    const float s = red[tid << 2] + red[(tid << 2) + 1] + red[(tid << 2) + 2] + red[(tid << 2) + 3];
    const int m = m0 + tid;
    logits[m] = (mask[(b << 11) + (m & 2047)] == 0) ? NEGV : s;
  }
}

// ---------------------------------------------------------------------------
// softmax over S=2048 per batch row -> attention weights (output 1)
// ---------------------------------------------------------------------------
__global__ void softmax_kernel(const float* __restrict__ logits, float* __restrict__ wout) {
  __shared__ float red[4];
  const int b = blockIdx.x, tid = threadIdx.x;
  const int wid = tid >> 6, lane = tid & 63;
  const float* lb = logits + b * 2048;
  float x[8];
  #pragma unroll
  for (int j = 0; j < 8; ++j) x[j] = lb[tid + j * 256];
  float m = x[0];
  #pragma unroll
  for (int j = 1; j < 8; ++j) m = fmaxf(m, x[j]);
  #pragma unroll
  for (int off = 32; off > 0; off >>= 1) m = fmaxf(m, __shfl_xor(m, off));
  if (lane == 0) red[wid] = m;
  __syncthreads();
  m = fmaxf(fmaxf(red[0], red[1]), fmaxf(red[2], red[3]));
  __syncthreads();
  float e[8];
  float s = 0.f;
  #pragma unroll
  for (int j = 0; j < 8; ++j) { e[j] = expf(x[j] - m); s += e[j]; }
  #pragma unroll
  for (int off = 32; off > 0; off >>= 1) s += __shfl_xor(s, off);
  if (lane == 0) red[wid] = s;
  __syncthreads();
  s = red[0] + red[1] + red[2] + red[3];
  const float inv = 1.0f / s;
  #pragma unroll
  for (int j = 0; j < 8; ++j) wout[b * 2048 + tid + j * 256] = e[j] * inv;
}

// ---------------------------------------------------------------------------
// context from fp16 enc: ctx[b,e] = sum_s w[b,s] * enc16[b,s,e]
// ---------------------------------------------------------------------------
__global__ void context16_kernel(const _Float16* __restrict__ enc16,
                                 const float* __restrict__ wout, float* __restrict__ ctx) {
  const int b = blockIdx.x >> 4;
  const int ch = blockIdx.x & 15;
  const int tl = threadIdx.x & 127;  // e-granule: 8 cols
  const int sh = threadIdx.x >> 7;   // 0/1: s interleave
  float a[8] = {0.f, 0.f, 0.f, 0.f, 0.f, 0.f, 0.f, 0.f};
  #pragma unroll 1
  for (int i = 0; i < 64; ++i) {
    const int s = (ch << 7) + (i << 1) + sh;
    const float w = wout[(b << 11) + s];
    const half8 r = *(const half8*)(enc16 + (((size_t)(b << 11) + s) << 10) + (tl << 3));
    #pragma unroll
    for (int j = 0; j < 8; ++j) a[j] = fmaf(w, (float)r[j], a[j]);
  }
  float* c = ctx + (b << 10) + (tl << 3);
  #pragma unroll
  for (int j = 0; j < 8; ++j) atomicAdd(c + j, a[j]);
}

// ---------------------------------------------------------------------------
extern "C" void kernel_launch(void* const* d_in, const int* in_sizes, int n_in,
                              void* d_out, int out_size, void* d_ws, size_t ws_size,
                              hipStream_t stream) {
  const float* hidden = (const float*)d_in[0];
  const float* enc    = (const float*)d_in[1];
  const int*   mask   = (const int*)d_in[2];
  const float* W_h    = (const float*)d_in[3];
  const float* b_h    = (const float*)d_in[4];
  const float* W_e    = (const float*)d_in[5];
  const float* b_e    = (const float*)d_in[6];
  const float* v      = (const float*)d_in[7];

  float* ctx  = (float*)d_out;              // context: 32*1024 floats
  float* wout = (float*)d_out + 32 * 1024;  // attention weights: 32*2048 floats

  char* ws = (char*)d_ws;
  const size_t ENC16_BYTES = 134217728ULL;  // 32*2048*1024 fp16
  _Float16* enc16 = (_Float16*)ws;
  _Float16* W16T  = (_Float16*)(ws + ENC16_BYTES);
  float* hpb      = (float*)(ws + ENC16_BYTES + 2097152);
  float* logits   = (float*)(ws + ENC16_BYTES + 2097152 + 131072);

  hipMemsetAsync(ctx, 0, 32 * 1024 * sizeof(float), stream);
  hipLaunchKernelGGL(prep_kernel, dim3(1152 + 32768), dim3(256), 0, stream,
                     enc, enc16, W_e, W16T, hidden, W_h, b_h, b_e, hpb);
  hipLaunchKernelGGL(attn_gemm8_kernel, dim3(512), dim3(256), 0, stream,
                     enc16, W16T, hpb, v, mask, logits);
  hipLaunchKernelGGL(softmax_kernel, dim3(32), dim3(256), 0, stream, logits, wout);
  hipLaunchKernelGGL(context16_kernel, dim3(512), dim3(256), 0, stream, enc16, wout, ctx);
}

// Round 14
// 257.005 us; speedup vs baseline: 1.4162x; 1.1528x over previous
//
#include <hip/hip_runtime.h>

#define NEGV -10000000000.0f

typedef _Float16 half8 __attribute__((ext_vector_type(8)));
typedef float f32x4 __attribute__((ext_vector_type(4)));

__device__ __forceinline__ void gld16(const void* g, void* l) {
  __builtin_amdgcn_global_load_lds((const __attribute__((address_space(1))) void*)g,
                                   (__attribute__((address_space(3))) void*)l,
                                   16, 0, 0);
}

__device__ __forceinline__ float fast_tanh(float x) {
  const float e = __expf(2.0f * x);
  return 1.0f - 2.0f * __builtin_amdgcn_rcpf(e + 1.0f);
}

// ---------------------------------------------------------------------------
// PREP (one launch): blocks [0,128) hproj | [128,1152) wconv.
// encconv is GONE: the GEMM stages A directly from fp32 (regs->cvt->ds_write),
// and context reads fp32 enc. No enc16 anywhere.
// ---------------------------------------------------------------------------
__global__ __launch_bounds__(256) void prep_kernel(
    const float* __restrict__ We, _Float16* __restrict__ W16T,
    const float* __restrict__ hidden, const float* __restrict__ W_h,
    const float* __restrict__ b_h, const float* __restrict__ b_e,
    float* __restrict__ hpb) {
  __shared__ float tile[32][33];
  const int bid = blockIdx.x;
  const int tid = threadIdx.x;

  if (bid < 128) {
    // ---- hproj ----
    const int b = bid >> 2;
    const int h = ((bid & 3) << 8) | tid;
    const float* hb = hidden + b * 1024;
    float a0 = 0.f, a1 = 0.f, a2 = 0.f, a3 = 0.f;
    #pragma unroll 4
    for (int k = 0; k < 1024; k += 4) {
      a0 = fmaf(hb[k + 0], W_h[(size_t)(k + 0) * 1024 + h], a0);
      a1 = fmaf(hb[k + 1], W_h[(size_t)(k + 1) * 1024 + h], a1);
      a2 = fmaf(hb[k + 2], W_h[(size_t)(k + 2) * 1024 + h], a2);
      a3 = fmaf(hb[k + 3], W_h[(size_t)(k + 3) * 1024 + h], a3);
    }
    hpb[b * 1024 + h] = b_h[h] + b_e[h] + ((a0 + a1) + (a2 + a3));
  } else {
    // ---- wconv: W16T[n][k] = (fp16) W_e[k][n] ----
    const int tb = bid - 128;
    const int n0 = (tb & 31) << 5, k0 = (tb >> 5) << 5;
    const int tx = tid & 31, ty = tid >> 5;  // 32 x 8
    #pragma unroll
    for (int i = 0; i < 4; ++i) {
      const int r = ty + (i << 3);
      tile[r][tx] = We[(size_t)(k0 + r) * 1024 + n0 + tx];
    }
    __syncthreads();
    #pragma unroll
    for (int i = 0; i < 4; ++i) {
      const int r = ty + (i << 3);
      W16T[(size_t)(n0 + r) * 1024 + k0 + tx] = (_Float16)tile[tx][r];
    }
  }
}

// ---------------------------------------------------------------------------
// FUSED GEMM = R9's measured-best schedule, A staged FROM FP32 in-loop:
//   logits[b,s] = mask ? v . tanh(hpb[b,:] + enc[b,s,:]@W_e) : NEG
// BM=256, BN=256 (4 panels), BK=32, 512 threads, 8 waves 2Mx4N, per-wave
// 128x64 (acc[8][4]).
//  - A: plain fp32 loads -> regs (af, tile t+1 held across the tile) ->
//    cvt fp16 -> dest-swizzled ds_write_b128 into 3-buffered 16KB tiles.
//    Dest-swizzle == gld_lds layout (LDS[row][g^swz] = true col g), so the
//    read side is unchanged. No global stores -> ledger stays exact.
//  - B: gld_lds from W16T (2MB, L2-resident), stage t+2, unchanged from R9.
//  - Ledger/tile (FIFO): start [A(t+1)x4, B(t+1)x2]; compiler's wait at the
//    cvt site retires A(t+1) (vmcnt(2)); issue [A(t+2)x4, B(t+2)x2] -> 8;
//    tile-end vmcnt(6) retires B(t+1), leaving 6 in flight. Never drains.
//    lgkmcnt(0) at tile end publishes the (long-retired) ds_writes.
//  - A fp32 is re-read per panel (4x, 1GB demand): enc = 256MB fits L3
//    exactly -> panels 2-4 should hit L3. FETCH_SIZE is the diagnostic.
// Swizzle: g ^= (row>>1)&3 (0-conflict, R4-R11).
// ---------------------------------------------------------------------------
__global__ __launch_bounds__(512, 2) void attn_gemm8_kernel(
    const float* __restrict__ enc32, const _Float16* __restrict__ W16T,
    const float* __restrict__ hpb, const float* __restrict__ v,
    const int* __restrict__ mask, float* __restrict__ logits) {
  __shared__ __align__(16) _Float16 Abuf[3][256 * 32];  // 48 KB
  __shared__ __align__(16) _Float16 Bbuf[3][256 * 32];  // 48 KB
  __shared__ float hp_s[1024];
  __shared__ float vh_s[1024];
  __shared__ float red[1024];

  const int tid = threadIdx.x;
  const int wid = tid >> 6;
  const int lane = tid & 63;
  const int l15 = lane & 15;
  const int qq = lane >> 4;        // 16B granule within the 64B row
  const int wr = wid >> 2;         // 0..1: rows [wr*128, +128)
  const int wc = wid & 3;          // 0..3: cols [wc*64, +64) within the panel
  const int m0 = blockIdx.x << 8;  // 256 rows per block
  const int b = blockIdx.x >> 3;   // 8 blocks per batch

  for (int i = tid; i < 1024; i += 512) {
    hp_s[i] = hpb[(b << 10) + i];
    vh_s[i] = v[i];
  }

  // ---- staging constants ----
  const int r0 = tid >> 2;                     // A/B row, issue 0 (0..127)
  const int r1 = r0 + 128;                     // issue 1 (same swz bits)
  const int g0 = tid & 3;                      // 16B granule within 64B row
  const int swzd = (g0 ^ ((r0 >> 1) & 3)) << 4;  // dest-swizzled LDS col byte
  const int scB = swzd;                          // B source col (inverse swz)
  const int ldsoff0 = (wid << 10);
  const int ldsoff1 = (wid << 10) + 8192;

  const float* encb = enc32 + (size_t)m0 * 1024;
  const char* wb0 = (const char*)W16T;

  // A: plain fp32 loads into regs (true col = g0*8 within the 32-wide k-tile)
  f32x4 af[4];
  auto issueA = [&](int t) {
    const float* p0 = encb + (size_t)r0 * 1024 + ((t & 31) << 5) + (g0 << 3);
    const float* p1 = encb + (size_t)r1 * 1024 + ((t & 31) << 5) + (g0 << 3);
    af[0] = *(const f32x4*)p0; af[1] = *(const f32x4*)(p0 + 4);
    af[2] = *(const f32x4*)p1; af[3] = *(const f32x4*)(p1 + 4);
  };
  auto writeA = [&](int buf) {
    half8 h0, h1;
    #pragma unroll
    for (int j = 0; j < 4; ++j) {
      h0[j] = (_Float16)af[0][j]; h0[4 + j] = (_Float16)af[1][j];
      h1[j] = (_Float16)af[2][j]; h1[4 + j] = (_Float16)af[3][j];
    }
    char* Ab = (char*)(&Abuf[buf][0]);
    *(half8*)(Ab + (r0 << 6) + swzd) = h0;
    *(half8*)(Ab + (r1 << 6) + swzd) = h1;
  };
  // B: gld_lds from W16T (unchanged from R9)
  auto stageB = [&](int buf, int t) {
    const char* wb = wb0 + ((size_t)(t >> 5) << 19);  // panel * 256*2048 B
    const int colb = ((t & 31) << 6) + scB;
    char* base = (char*)(&Bbuf[buf][0]);
    gld16(wb + (size_t)r0 * 2048 + colb, base + ldsoff0);
    gld16(wb + (size_t)r1 * 2048 + colb, base + ldsoff1);
  };

  // ---- read-side offsets (loop-invariant, swizzled; unchanged) ----
  int aoff[2][4], boff[4];
  #pragma unroll
  for (int mh = 0; mh < 2; ++mh)
    #pragma unroll
    for (int mi = 0; mi < 4; ++mi) {
      const int row = (wr << 7) + (mh << 6) + (mi << 4) + l15;
      aoff[mh][mi] = (row << 6) + ((qq ^ ((row >> 1) & 3)) << 4);
    }
  #pragma unroll
  for (int ni = 0; ni < 4; ++ni) {
    const int np = (wc << 6) + (ni << 4) + l15;
    boff[ni] = (np << 6) + ((qq ^ ((np >> 1) & 3)) << 4);
  }

  f32x4 acc[8][4];
  float rowsum[8][4];
  #pragma unroll
  for (int mi = 0; mi < 8; ++mi)
    #pragma unroll
    for (int j = 0; j < 4; ++j) {
      acc[mi][j] = (f32x4){0.f, 0.f, 0.f, 0.f};
      rowsum[mi][j] = 0.f;
    }

  // ---- prologue: A(0)->buf0 via regs; B(0),B(1) staged; af <- A(1) ----
  issueA(0);
  stageB(0, 0); stageB(1, 1);
  asm volatile("s_waitcnt vmcnt(4)" ::: "memory");  // A(0) regs ready
  writeA(0);
  issueA(1);
  __syncthreads();  // full drain: B(0),B(1) landed, A(0) published

  #pragma unroll 1
  for (int t = 0; t < 128; ++t) {
    const int bi = t % 3;
    const int bi1 = (bi >= 2) ? 0 : bi + 1;       // (t+1)%3
    const int bi2 = (bi1 >= 2) ? 0 : bi1 + 1;     // (t+2)%3
    const char* A = (const char*)(&Abuf[bi][0]);
    const char* B = (const char*)(&Bbuf[bi][0]);
    half8 a0[4], a1[4], bf[4];

    // ---- issue all 12 ds_reads up front (compiler places counted waits) ----
    #pragma unroll
    for (int mi = 0; mi < 4; ++mi) a0[mi] = *(const half8*)(A + aoff[0][mi]);
    #pragma unroll
    for (int ni = 0; ni < 4; ++ni) bf[ni] = *(const half8*)(B + boff[ni]);
    #pragma unroll
    for (int mi = 0; mi < 4; ++mi) a1[mi] = *(const half8*)(A + aoff[1][mi]);

    // ---- cvt + write A(t+1) (af loaded during t-1; compiler waits vmcnt) ----
    if (t < 127) writeA(bi1);
    // ---- issue next loads: A(t+2) regs, B(t+2) gld_lds ----
    if (t < 126) { issueA(t + 2); stageB(bi2, t + 2); }

    // ---- MFMA clusters; reads drain underneath via per-operand waits ----
    __builtin_amdgcn_s_setprio(1);
    #pragma unroll
    for (int mi = 0; mi < 4; ++mi)
      #pragma unroll
      for (int ni = 0; ni < 4; ++ni)
        acc[mi][ni] = __builtin_amdgcn_mfma_f32_16x16x32_f16(a0[mi], bf[ni], acc[mi][ni], 0, 0, 0);
    #pragma unroll
    for (int mi = 0; mi < 4; ++mi)
      #pragma unroll
      for (int ni = 0; ni < 4; ++ni)
        acc[4 + mi][ni] = __builtin_amdgcn_mfma_f32_16x16x32_f16(a1[mi], bf[ni], acc[4 + mi][ni], 0, 0, 0);
    __builtin_amdgcn_s_setprio(0);

    // ---- tile-end sync: counted vmcnt; publish ds_writes; barrier ----
    if (t < 126) asm volatile("s_waitcnt vmcnt(6)" ::: "memory");
    else         asm volatile("s_waitcnt vmcnt(0)" ::: "memory");
    asm volatile("s_waitcnt lgkmcnt(0)" ::: "memory");
    __builtin_amdgcn_s_barrier();

    // ---- per-panel epilogue: rowsum += tanh(acc + hproj) * v ----
    if ((t & 31) == 31) {
      const int nt = t >> 5;
      const int hb = (nt << 8) + (wc << 6);
      #pragma unroll
      for (int ni = 0; ni < 4; ++ni) {
        const int h = hb + (ni << 4) + l15;
        const float hv = hp_s[h];
        const float vv = vh_s[h];
        #pragma unroll
        for (int mi = 0; mi < 8; ++mi) {
          #pragma unroll
          for (int r = 0; r < 4; ++r)
            rowsum[mi][r] += fast_tanh(acc[mi][ni][r] + hv) * vv;
          acc[mi][ni] = (f32x4){0.f, 0.f, 0.f, 0.f};
        }
      }
    }
  }

  // ---- reduce across the 16 column-lanes of each wave ----
  #pragma unroll
  for (int mi = 0; mi < 8; ++mi)
    #pragma unroll
    for (int r = 0; r < 4; ++r) {
      float s = rowsum[mi][r];
      s += __shfl_xor(s, 1);
      s += __shfl_xor(s, 2);
      s += __shfl_xor(s, 4);
      s += __shfl_xor(s, 8);
      rowsum[mi][r] = s;
    }
  __syncthreads();
  if (l15 == 0) {
    #pragma unroll
    for (int mi = 0; mi < 8; ++mi)
      #pragma unroll
      for (int r = 0; r < 4; ++r) {
        const int row = (wr << 7) + (mi << 4) + (qq << 2) + r;
        red[(row << 2) + wc] = rowsum[mi][r];
      }
  }
  __syncthreads();
  if (tid < 256) {
    const float s = red[tid << 2] + red[(tid << 2) + 1] + red[(tid << 2) + 2] + red[(tid << 2) + 3];
    const int m = m0 + tid;
    logits[m] = (mask[(b << 11) + (m & 2047)] == 0) ? NEGV : s;
  }
}

// ---------------------------------------------------------------------------
// softmax over S=2048 per batch row -> attention weights (output 1)
// ---------------------------------------------------------------------------
__global__ void softmax_kernel(const float* __restrict__ logits, float* __restrict__ wout) {
  __shared__ float red[4];
  const int b = blockIdx.x, tid = threadIdx.x;
  const int wid = tid >> 6, lane = tid & 63;
  const float* lb = logits + b * 2048;
  float x[8];
  #pragma unroll
  for (int j = 0; j < 8; ++j) x[j] = lb[tid + j * 256];
  float m = x[0];
  #pragma unroll
  for (int j = 1; j < 8; ++j) m = fmaxf(m, x[j]);
  #pragma unroll
  for (int off = 32; off > 0; off >>= 1) m = fmaxf(m, __shfl_xor(m, off));
  if (lane == 0) red[wid] = m;
  __syncthreads();
  m = fmaxf(fmaxf(red[0], red[1]), fmaxf(red[2], red[3]));
  __syncthreads();
  float e[8];
  float s = 0.f;
  #pragma unroll
  for (int j = 0; j < 8; ++j) { e[j] = expf(x[j] - m); s += e[j]; }
  #pragma unroll
  for (int off = 32; off > 0; off >>= 1) s += __shfl_xor(s, off);
  if (lane == 0) red[wid] = s;
  __syncthreads();
  s = red[0] + red[1] + red[2] + red[3];
  const float inv = 1.0f / s;
  #pragma unroll
  for (int j = 0; j < 8; ++j) wout[b * 2048 + tid + j * 256] = e[j] * inv;
}

// ---------------------------------------------------------------------------
// context from fp32 enc: ctx[b,e] = sum_s w[b,s] * enc[b,s,e]
// ---------------------------------------------------------------------------
__global__ void context_kernel(const float* __restrict__ enc, const float* __restrict__ wout,
                               float* __restrict__ ctx) {
  const int b = blockIdx.x >> 4;
  const int ch = blockIdx.x & 15;
  const int tid = threadIdx.x;
  float ax = 0.f, ay = 0.f, az = 0.f, aw = 0.f;
  const int s0 = ch * 128;
  for (int i = 0; i < 128; ++i) {
    const int s = s0 + i;
    const float w = wout[b * 2048 + s];
    const float4 r = *(const float4*)(enc + (size_t)(b * 2048 + s) * 1024 + tid * 4);
    ax = fmaf(w, r.x, ax);
    ay = fmaf(w, r.y, ay);
    az = fmaf(w, r.z, az);
    aw = fmaf(w, r.w, aw);
  }
  float* c = ctx + b * 1024 + tid * 4;
  atomicAdd(c + 0, ax);
  atomicAdd(c + 1, ay);
  atomicAdd(c + 2, az);
  atomicAdd(c + 3, aw);
}

// ---------------------------------------------------------------------------
extern "C" void kernel_launch(void* const* d_in, const int* in_sizes, int n_in,
                              void* d_out, int out_size, void* d_ws, size_t ws_size,
                              hipStream_t stream) {
  const float* hidden = (const float*)d_in[0];
  const float* enc    = (const float*)d_in[1];
  const int*   mask   = (const int*)d_in[2];
  const float* W_h    = (const float*)d_in[3];
  const float* b_h    = (const float*)d_in[4];
  const float* W_e    = (const float*)d_in[5];
  const float* b_e    = (const float*)d_in[6];
  const float* v      = (const float*)d_in[7];

  float* ctx  = (float*)d_out;              // context: 32*1024 floats
  float* wout = (float*)d_out + 32 * 1024;  // attention weights: 32*2048 floats

  char* ws = (char*)d_ws;
  _Float16* W16T = (_Float16*)ws;                                   // 2 MB
  float* hpb     = (float*)(ws + 2097152);                          // 128 KB
  float* logits  = (float*)(ws + 2097152 + 131072);                 // 256 KB

  hipMemsetAsync(ctx, 0, 32 * 1024 * sizeof(float), stream);
  hipLaunchKernelGGL(prep_kernel, dim3(1152), dim3(256), 0, stream,
                     W_e, W16T, hidden, W_h, b_h, b_e, hpb);
  hipLaunchKernelGGL(attn_gemm8_kernel, dim3(256), dim3(512), 0, stream,
                     enc, W16T, hpb, v, mask, logits);
  hipLaunchKernelGGL(softmax_kernel, dim3(32), dim3(256), 0, stream, logits, wout);
  hipLaunchKernelGGL(context_kernel, dim3(512), dim3(256), 0, stream, enc, wout, ctx);
}